// Round 5
// baseline (544.220 us; speedup 1.0000x reference)
//
#include <hip/hip_runtime.h>

#define B 4
#define N 2048
#define MAXIT 11        // bodies it=0..10
#define TOL 1e-4f
#define BT 256
#define NBLK 256
#define CC 64          // candidates per nn tile
#define QPT 4          // queries per thread
#define QC (BT*QPT)    // 1024 queries per nn tile
#define RPT 8          // rows per thread in phase-1 (N/BT)

// ---------------- workspace layout ----------------
// [0,      65536)   u64 nnA[B][N]          (slot 0, parity-encoded, never reset)
// [65536, 131072)   u64 nnB[B][N]          (slot 1, parity-encoded, never reset)
// [131072,131080)   uint bar[2]            {cnt, flag} for global barrier

// ---------------- 3x3 helpers (double, thread-serial) ----------------
__device__ double det3(const double* M) {
    return M[0]*(M[4]*M[8]-M[5]*M[7])
         - M[1]*(M[3]*M[8]-M[5]*M[6])
         + M[2]*(M[3]*M[7]-M[4]*M[6]);
}

__device__ void svd3x3(const double* A, double* U, double* V, double* sig) {
    double S[9];
    for (int i = 0; i < 3; ++i)
        for (int j = 0; j < 3; ++j) {
            double s = 0.0;
            for (int k = 0; k < 3; ++k) s += A[k*3+i] * A[k*3+j];
            S[i*3+j] = s;
        }
    double Vm[9] = {1,0,0, 0,1,0, 0,0,1};
    for (int sweep = 0; sweep < 30; ++sweep) {
        double off = fabs(S[1]) + fabs(S[2]) + fabs(S[5]);
        double base = fabs(S[0]) + fabs(S[4]) + fabs(S[8]);
        if (off <= 1e-15 * base) break;
        for (int pi = 0; pi < 3; ++pi) {
            const int p = (pi == 2) ? 1 : 0;
            const int q = (pi == 0) ? 1 : 2;
            double apq = S[p*3+q];
            if (apq == 0.0) continue;
            double app = S[p*3+p], aqq = S[q*3+q];
            double tau = (aqq - app) / (2.0 * apq);
            double tt  = ((tau >= 0.0) ? 1.0 : -1.0) / (fabs(tau) + sqrt(1.0 + tau*tau));
            double c = 1.0 / sqrt(1.0 + tt*tt);
            double s = tt * c;
            for (int k = 0; k < 3; ++k) {
                double skp = S[k*3+p], skq = S[k*3+q];
                S[k*3+p] = c*skp - s*skq;
                S[k*3+q] = s*skp + c*skq;
            }
            for (int k = 0; k < 3; ++k) {
                double spk = S[p*3+k], sqk = S[q*3+k];
                S[p*3+k] = c*spk - s*sqk;
                S[q*3+k] = s*spk + c*sqk;
            }
            for (int k = 0; k < 3; ++k) {
                double vkp = Vm[k*3+p], vkq = Vm[k*3+q];
                Vm[k*3+p] = c*vkp - s*vkq;
                Vm[k*3+q] = s*vkp + c*vkq;
            }
        }
    }
    double lam[3] = {S[0], S[4], S[8]};
    int ord[3] = {0, 1, 2};
    for (int i = 0; i < 2; ++i)
        for (int j = i+1; j < 3; ++j)
            if (lam[ord[j]] > lam[ord[i]]) { int tmp = ord[i]; ord[i] = ord[j]; ord[j] = tmp; }
    for (int i = 0; i < 3; ++i) {
        int o = ord[i];
        double l = lam[o] > 0.0 ? lam[o] : 0.0;
        sig[i] = sqrt(l);
        for (int k = 0; k < 3; ++k) V[k*3+i] = Vm[k*3+o];
    }
    for (int i = 0; i < 3; ++i) {
        double u0 = 0, u1 = 0, u2 = 0;
        for (int k = 0; k < 3; ++k) {
            u0 += A[0*3+k] * V[k*3+i];
            u1 += A[1*3+k] * V[k*3+i];
            u2 += A[2*3+k] * V[k*3+i];
        }
        double nrm = sqrt(u0*u0 + u1*u1 + u2*u2);
        if (nrm > 1e-300) { u0 /= nrm; u1 /= nrm; u2 /= nrm; }
        else {
            double ax = U[0], ay = U[3], az = U[6];
            double bx = U[1], by = U[4], bz = U[7];
            u0 = ay*bz - az*by; u1 = az*bx - ax*bz; u2 = ax*by - ay*bx;
        }
        U[0*3+i] = u0; U[1*3+i] = u1; U[2*3+i] = u2;
    }
}

// R = V @ U^T (reference's R with the V[2][2]*=d quirk). Fast path: when
// det(H) > 0 the quirk is a no-op (d=+1) and R is exactly the transpose of
// the orthogonal polar factor of H -> Newton polar iteration, fixed 10
// iterations (uniform control flow, bit-identical across blocks).
// Fallback (det<=eps): exact Jacobi path.
__device__ void compute_R_f64(const double* H, double* R) {
    double nf = 0.0;
    for (int k = 0; k < 9; ++k) nf += H[k]*H[k];
    if (nf > 0.0) {
        const double sc = 1.0 / sqrt(nf * (1.0/3.0));
        double X[9];
        #pragma unroll
        for (int k = 0; k < 9; ++k) X[k] = H[k] * sc;
        const double d0 = det3(X);
        if (d0 > 1e-12) {
            for (int iter = 0; iter < 10; ++iter) {
                const double dt = det3(X);
                const double g = (iter < 4) ? cbrt(1.0 / dt) : 1.0;
                double Y[9];
                #pragma unroll
                for (int k = 0; k < 9; ++k) Y[k] = g * X[k];
                double C[9];                       // cofactor matrix: Y^{-T} = C/det(Y)
                C[0] = Y[4]*Y[8]-Y[5]*Y[7]; C[1] = Y[5]*Y[6]-Y[3]*Y[8]; C[2] = Y[3]*Y[7]-Y[4]*Y[6];
                C[3] = Y[2]*Y[7]-Y[1]*Y[8]; C[4] = Y[0]*Y[8]-Y[2]*Y[6]; C[5] = Y[1]*Y[6]-Y[0]*Y[7];
                C[6] = Y[1]*Y[5]-Y[2]*Y[4]; C[7] = Y[2]*Y[3]-Y[0]*Y[5]; C[8] = Y[0]*Y[4]-Y[1]*Y[3];
                const double inv = 1.0 / (dt * g * g * g);
                #pragma unroll
                for (int k = 0; k < 9; ++k) X[k] = 0.5 * (Y[k] + C[k] * inv);
            }
            R[0]=X[0]; R[1]=X[3]; R[2]=X[6];
            R[3]=X[1]; R[4]=X[4]; R[5]=X[7];
            R[6]=X[2]; R[7]=X[5]; R[8]=X[8];
            return;
        }
    }
    double U[9], V[9], sig[3];
    svd3x3(H, U, V, sig);
    double d = (det3(U) * det3(V) < 0.0) ? -1.0 : 1.0;
    V[2*3+2] *= d;
    for (int i = 0; i < 3; ++i)
        for (int j = 0; j < 3; ++j) {
            double s = 0.0;
            for (int k = 0; k < 3; ++k) s += V[i*3+k] * U[j*3+k];
            R[i*3+j] = s;
        }
}

__device__ inline float wred(float v) {
    v += __shfl_down(v, 32);
    v += __shfl_down(v, 16);
    v += __shfl_down(v, 8);
    v += __shfl_down(v, 4);
    v += __shfl_down(v, 2);
    v += __shfl_down(v, 1);
    return v;   // valid on lane 0 of each wave
}

__device__ __forceinline__ void tf3(const float* __restrict__ R, const float* __restrict__ T,
                                    float x, float y, float z,
                                    float& ox, float& oy, float& oz) {
    ox = x*R[0] + y*R[3] + z*R[6] + T[0];
    oy = x*R[1] + y*R[4] + z*R[7] + T[1];
    oz = x*R[2] + y*R[5] + z*R[8] + T[2];
}

// Lightweight grid barrier: sense-reversing, agent-scope atomics only.
// No L2 writeback (unlike cg::grid.sync's ~33us) — all cross-block data
// flows through device-scope atomics / agent-scope loads.
__device__ __forceinline__ void gbar(unsigned int* cnt, unsigned int* flag,
                                     unsigned int& sense) {
    __syncthreads();   // drains this block's vmcnt (incl. atomicMin writes)
    if (threadIdx.x == 0) {
        sense ^= 1u;
        unsigned int arrived = __hip_atomic_fetch_add(cnt, 1u, __ATOMIC_ACQ_REL,
                                                      __HIP_MEMORY_SCOPE_AGENT);
        if (arrived == NBLK - 1) {
            __hip_atomic_store(cnt, 0u, __ATOMIC_RELAXED, __HIP_MEMORY_SCOPE_AGENT);
            __hip_atomic_store(flag, sense, __ATOMIC_RELEASE, __HIP_MEMORY_SCOPE_AGENT);
        } else {
            while (__hip_atomic_load(flag, __ATOMIC_ACQUIRE,
                                     __HIP_MEMORY_SCOPE_AGENT) != sense)
                __builtin_amdgcn_s_sleep(4);
        }
    }
    __syncthreads();
}

__device__ __forceinline__ unsigned long long nnld(const unsigned long long* p) {
    return __hip_atomic_load(p, __ATOMIC_RELAXED, __HIP_MEMORY_SCOPE_AGENT);
}

// Persistent cooperative kernel: whole ICP loop, 1 global barrier per iteration.
// 256 blocks: b = bid>>6, blk = bid&63. R,t/err/done computed redundantly in
// every block from identical-order reductions (bit-identical f64) -> uniform
// control flow. Cross-block state: nn only (atomicMin writes, agent loads).
__global__ void __launch_bounds__(BT, 1)
icp_pers(const float* __restrict__ p1, const float* __restrict__ p2,
         float* __restrict__ out,
         unsigned long long* __restrict__ nnA,
         unsigned long long* __restrict__ nnB,
         unsigned int* __restrict__ bar) {
    const int bid = blockIdx.x, tid = threadIdx.x;
    const int b = bid >> 6, blk = bid & 63;
    const int lane = tid & 63, wave = tid >> 6;

    __shared__ float4 sc4[CC];
    __shared__ float sR[9], sT[3];
    __shared__ double sCum[12];
    __shared__ float lred[4][16];
    __shared__ int sFin;

    unsigned int sense = 0;
    float prevErr = 0.0f;     // meaningful on tid==0 only

    if (tid == 0) {
        sR[0]=1.f; sR[1]=0.f; sR[2]=0.f;
        sR[3]=0.f; sR[4]=1.f; sR[5]=0.f;
        sR[6]=0.f; sR[7]=0.f; sR[8]=1.f;
        sT[0]=0.f; sT[1]=0.f; sT[2]=0.f;
        sCum[0]=1; sCum[1]=0; sCum[2]=0; sCum[3]=0; sCum[4]=1; sCum[5]=0;
        sCum[6]=0; sCum[7]=0; sCum[8]=1; sCum[9]=0; sCum[10]=0; sCum[11]=0;
        sFin = 0;
    }
    __syncthreads();

    for (int it = 0; it <= MAXIT; ++it) {
        if (it > 0) {
            // ---------- phase 1: reduce nn[it-1], polar, compose ----------
            const unsigned long long* nnR = ((it-1) & 1) ? nnB : nnA;
            const int renc = ((it-1) >> 1) & 1;
            float cR[9], cT[3];
            #pragma unroll
            for (int k = 0; k < 9; ++k) cR[k] = sR[k];
            #pragma unroll
            for (int k = 0; k < 3; ++k) cT[k] = sT[k];

            float pv[16];
            #pragma unroll
            for (int k = 0; k < 16; ++k) pv[k] = 0.f;

            unsigned long long pk3[RPT];
            #pragma unroll
            for (int u = 0; u < RPT; ++u)
                pk3[u] = nnld(&nnR[3*N + (tid + u*BT)]);   // reference quirk: idx[-1]
            int mi[RPT];
            #pragma unroll
            for (int u = 0; u < RPT; ++u) {
                const unsigned long long k3 = renc ? ~pk3[u] : pk3[u];
                mi[u] = (int)(unsigned int)(k3 & 0xffffffffULL);
            }
            float mxa[RPT], mya[RPT], mza[RPT];
            #pragma unroll
            for (int u = 0; u < RPT; ++u) {
                const float* mp = &p2[(b*N + mi[u])*3];
                mxa[u] = mp[0]; mya[u] = mp[1]; mza[u] = mp[2];
            }
            float pxa[RPT], pya[RPT], pza[RPT];
            #pragma unroll
            for (int u = 0; u < RPT; ++u) {
                const float* pp = &p1[(b*N + (tid + u*BT))*3];
                pxa[u] = pp[0]; pya[u] = pp[1]; pza[u] = pp[2];
            }
            #pragma unroll
            for (int u = 0; u < RPT; ++u) {
                float tx, ty, tz;
                tf3(cR, cT, pxa[u], pya[u], pza[u], tx, ty, tz);   // temp_{it-1}
                const float mx = mxa[u], my = mya[u], mz = mza[u];
                pv[0] += mx;  pv[1] += my;  pv[2] += mz;
                pv[3] += tx;  pv[4] += ty;  pv[5] += tz;
                pv[6] += mx*tx;  pv[7]  += mx*ty;  pv[8]  += mx*tz;
                pv[9] += my*tx;  pv[10] += my*ty;  pv[11] += my*tz;
                pv[12]+= mz*tx;  pv[13] += mz*ty;  pv[14] += mz*tz;
            }
            for (int r = tid; r < B*N; r += BT) {            // err over ALL batches
                unsigned long long pk = nnld(&nnR[r]);
                if (renc) pk = ~pk;
                pv[15] += sqrtf(__uint_as_float((unsigned int)(pk >> 32)));
            }
            #pragma unroll
            for (int k = 0; k < 16; ++k) pv[k] = wred(pv[k]);
            if (lane == 0) {
                #pragma unroll
                for (int k = 0; k < 16; ++k) lred[wave][k] = pv[k];
            }
            __syncthreads();
            if (tid == 0) {
                float a[16];
                #pragma unroll
                for (int k = 0; k < 16; ++k)
                    a[k] = lred[0][k] + lred[1][k] + lred[2][k] + lred[3][k];
                const float errcur  = a[15] / (float)(B*N);
                const float errprev = (it >= 2) ? prevErr : 0.0f;
                const int done = (fabsf(errprev - errcur) < TOL) ? 1 : 0;
                prevErr = errcur;

                double c2d[3] = { (double)a[0]/N, (double)a[1]/N, (double)a[2]/N };
                double c1d[3] = { (double)a[3]/N, (double)a[4]/N, (double)a[5]/N };
                double H[9];
                for (int j = 0; j < 3; ++j)
                    for (int k = 0; k < 3; ++k)
                        H[j*3+k] = (double)a[6 + j*3 + k] - (double)N * c2d[j] * c1d[k];
                double Rinc[9], tinc[3];
                compute_R_f64(H, Rinc);
                for (int j = 0; j < 3; ++j)
                    tinc[j] = c2d[j] - (c1d[0]*Rinc[0*3+j] + c1d[1]*Rinc[1*3+j] + c1d[2]*Rinc[2*3+j]);
                // compose: Rc_new = Rc_old @ Rinc ; tc_new = tc_old @ Rinc + tinc
                double Rn[9], tn[3];
                for (int i = 0; i < 3; ++i)
                    for (int j = 0; j < 3; ++j)
                        Rn[i*3+j] = sCum[i*3+0]*Rinc[0*3+j] + sCum[i*3+1]*Rinc[1*3+j] + sCum[i*3+2]*Rinc[2*3+j];
                for (int j = 0; j < 3; ++j)
                    tn[j] = sCum[9+0]*Rinc[0*3+j] + sCum[9+1]*Rinc[1*3+j] + sCum[9+2]*Rinc[2*3+j] + tinc[j];
                for (int k = 0; k < 9; ++k) { sCum[k] = Rn[k]; sR[k] = (float)Rn[k]; }
                for (int k = 0; k < 3; ++k) { sCum[9+k] = tn[k]; sT[k] = (float)tn[k]; }
                sFin = (done || it == MAXIT) ? 1 : 0;
            }
            __syncthreads();
            if (sFin) break;      // uniform across all blocks (bit-identical f64)
        }

        // ---------- phase 2: NN for iteration it ----------
        {
            unsigned long long* nnW = (it & 1) ? nnB : nnA;
            const int wenc = (it >> 1) & 1;
            const int cb = (blk >> 1) * CC;
            const int qb = (blk & 1) * QC;
            if (tid < CC) {
                const float* cp = &p1[(b*N + cb + tid)*3];
                float cx, cy, cz;
                tf3(sR, sT, cp[0], cp[1], cp[2], cx, cy, cz);
                sc4[tid] = make_float4(cx, cy, cz, 0.5f*(cx*cx + cy*cy + cz*cz));
            }
            __syncthreads();
            float px[QPT], py[QPT], pz[QPT];
            float best[QPT];
            int   bi[QPT];
            #pragma unroll
            for (int k = 0; k < QPT; ++k) {
                const int q = qb + tid + BT*k;
                px[k] = p2[(b*N + q)*3 + 0];
                py[k] = p2[(b*N + q)*3 + 1];
                pz[k] = p2[(b*N + q)*3 + 2];
                best[k] = __uint_as_float(0x7f7fffffu);   // FLT_MAX
                bi[k] = 0;
            }
            #pragma unroll 4
            for (int j = 0; j < CC; ++j) {
                const float4 c = sc4[j];
                #pragma unroll
                for (int k = 0; k < QPT; ++k) {
                    float s = __builtin_fmaf(-px[k], c.x,
                              __builtin_fmaf(-py[k], c.y,
                              __builtin_fmaf(-pz[k], c.z, c.w)));
                    if (s < best[k]) { best[k] = s; bi[k] = cb + j; }
                }
            }
            #pragma unroll
            for (int k = 0; k < QPT; ++k) {
                const int q = qb + tid + BT*k;
                const float pn = px[k]*px[k] + py[k]*py[k] + pz[k]*pz[k];
                float d2 = fmaxf(__builtin_fmaf(2.0f, best[k], pn), 0.0f);
                unsigned long long K =
                    ((unsigned long long)__float_as_uint(d2) << 32) | (unsigned int)bi[k];
                if (wenc) atomicMax(&nnW[b*N + q], ~K);
                else      atomicMin(&nnW[b*N + q],  K);
            }
        }
        gbar(&bar[0], &bar[1], sense);   // NN writes -> next phase-1 reads
    }

    // ---------- finalize: _get_transform(p1, temp_final) ----------
    if (blk != 0) return;
    {
        float pv[16];
        #pragma unroll
        for (int k = 0; k < 16; ++k) pv[k] = 0.f;
        for (int i = tid; i < N; i += BT) {
            const float* pp = &p1[(b*N + i)*3];
            const float px = pp[0], py = pp[1], pz = pp[2];
            float tx, ty, tz;
            tf3(sR, sT, px, py, pz, tx, ty, tz);        // temp_final
            pv[0] += tx; pv[1] += ty; pv[2] += tz;
            pv[3] += px; pv[4] += py; pv[5] += pz;
            pv[6] += tx*px;  pv[7]  += tx*py;  pv[8]  += tx*pz;
            pv[9] += ty*px;  pv[10] += ty*py;  pv[11] += ty*pz;
            pv[12]+= tz*px;  pv[13] += tz*py;  pv[14] += tz*pz;
        }
        #pragma unroll
        for (int k = 0; k < 15; ++k) pv[k] = wred(pv[k]);
        if (lane == 0) {
            #pragma unroll
            for (int k = 0; k < 15; ++k) lred[wave][k] = pv[k];
        }
        __syncthreads();
        if (tid == 0) {
            float a[15];
            #pragma unroll
            for (int k = 0; k < 15; ++k)
                a[k] = lred[0][k] + lred[1][k] + lred[2][k] + lred[3][k];
            double c2d[3] = { (double)a[0]/N, (double)a[1]/N, (double)a[2]/N };
            double c1d[3] = { (double)a[3]/N, (double)a[4]/N, (double)a[5]/N };
            double H[9];
            for (int j = 0; j < 3; ++j)
                for (int k = 0; k < 3; ++k)
                    H[j*3+k] = (double)a[6 + j*3 + k] - (double)N * c2d[j] * c1d[k];
            double Rf[9];
            compute_R_f64(H, Rf);
            for (int i = 0; i < 3; ++i) {
                out[b*12 + i*4 + 0] = (float)Rf[i*3+0];
                out[b*12 + i*4 + 1] = (float)Rf[i*3+1];
                out[b*12 + i*4 + 2] = (float)Rf[i*3+2];
                const double tj = c2d[i] - (c1d[0]*Rf[0*3+i] + c1d[1]*Rf[1*3+i] + c1d[2]*Rf[2*3+i]);
                out[b*12 + i*4 + 3] = (float)tj;
            }
        }
    }
}

extern "C" void kernel_launch(void* const* d_in, const int* in_sizes, int n_in,
                              void* d_out, int out_size, void* d_ws, size_t ws_size,
                              hipStream_t stream) {
    const float* p1 = (const float*)d_in[0];
    const float* p2 = (const float*)d_in[1];
    float* out = (float*)d_out;
    unsigned long long* nnA = (unsigned long long*)d_ws;
    unsigned long long* nnB = (unsigned long long*)((char*)d_ws + 65536);
    unsigned int* bar = (unsigned int*)((char*)d_ws + 131072);

    hipMemsetAsync(d_ws, 0xFF, 131072, stream);                  // nn slots: all-ones
    hipMemsetAsync((char*)d_ws + 131072, 0, 8, stream);          // barrier state
    void* args[] = { (void*)&p1, (void*)&p2, (void*)&out,
                     (void*)&nnA, (void*)&nnB, (void*)&bar };
    hipLaunchCooperativeKernel((const void*)icp_pers, dim3(NBLK), dim3(BT),
                               args, 0, stream);
}

// Round 6
// 352.101 us; speedup vs baseline: 1.5456x; 1.5456x over previous
//
#include <hip/hip_runtime.h>

#define B 4
#define N 2048
#define MAXIT 11        // bodies it=0..10; launch it=11 is finalize-only
#define TOL 1e-4f
#define BT 256
#define NBLK 256
#define RPT 8          // rows per thread in phase-1 (N/BT)
#define QPB 32         // queries per block (N / 64 blocks-per-batch)
#define NSTR 32        // candidate stripes per block
#define CPS 64         // candidates per stripe (N/NSTR)

// ---------------- workspace layout ----------------
// [0,      65536)   u64 nnA[B][N]          (plain {d2bits,idx}, ping)
// [65536, 131072)   u64 nnB[B][N]          (plain {d2bits,idx}, pong)
// [131072,135680)   double rc[B][12][12]   (cumulative R(9)+t(3) per batch per it)
// [135680,135728)   float errs[12]
// [135728,135732)   int doneflag

// ---------------- 3x3 helpers (double, thread-serial) ----------------
__device__ double det3(const double* M) {
    return M[0]*(M[4]*M[8]-M[5]*M[7])
         - M[1]*(M[3]*M[8]-M[5]*M[6])
         + M[2]*(M[3]*M[7]-M[4]*M[6]);
}

__device__ void svd3x3(const double* A, double* U, double* V, double* sig) {
    double S[9];
    for (int i = 0; i < 3; ++i)
        for (int j = 0; j < 3; ++j) {
            double s = 0.0;
            for (int k = 0; k < 3; ++k) s += A[k*3+i] * A[k*3+j];
            S[i*3+j] = s;
        }
    double Vm[9] = {1,0,0, 0,1,0, 0,0,1};
    for (int sweep = 0; sweep < 30; ++sweep) {
        double off = fabs(S[1]) + fabs(S[2]) + fabs(S[5]);
        double base = fabs(S[0]) + fabs(S[4]) + fabs(S[8]);
        if (off <= 1e-15 * base) break;
        for (int pi = 0; pi < 3; ++pi) {
            const int p = (pi == 2) ? 1 : 0;
            const int q = (pi == 0) ? 1 : 2;
            double apq = S[p*3+q];
            if (apq == 0.0) continue;
            double app = S[p*3+p], aqq = S[q*3+q];
            double tau = (aqq - app) / (2.0 * apq);
            double tt  = ((tau >= 0.0) ? 1.0 : -1.0) / (fabs(tau) + sqrt(1.0 + tau*tau));
            double c = 1.0 / sqrt(1.0 + tt*tt);
            double s = tt * c;
            for (int k = 0; k < 3; ++k) {
                double skp = S[k*3+p], skq = S[k*3+q];
                S[k*3+p] = c*skp - s*skq;
                S[k*3+q] = s*skp + c*skq;
            }
            for (int k = 0; k < 3; ++k) {
                double spk = S[p*3+k], sqk = S[q*3+k];
                S[p*3+k] = c*spk - s*sqk;
                S[q*3+k] = s*spk + c*sqk;
            }
            for (int k = 0; k < 3; ++k) {
                double vkp = Vm[k*3+p], vkq = Vm[k*3+q];
                Vm[k*3+p] = c*vkp - s*vkq;
                Vm[k*3+q] = s*vkp + c*vkq;
            }
        }
    }
    double lam[3] = {S[0], S[4], S[8]};
    int ord[3] = {0, 1, 2};
    for (int i = 0; i < 2; ++i)
        for (int j = i+1; j < 3; ++j)
            if (lam[ord[j]] > lam[ord[i]]) { int tmp = ord[i]; ord[i] = ord[j]; ord[j] = tmp; }
    for (int i = 0; i < 3; ++i) {
        int o = ord[i];
        double l = lam[o] > 0.0 ? lam[o] : 0.0;
        sig[i] = sqrt(l);
        for (int k = 0; k < 3; ++k) V[k*3+i] = Vm[k*3+o];
    }
    for (int i = 0; i < 3; ++i) {
        double u0 = 0, u1 = 0, u2 = 0;
        for (int k = 0; k < 3; ++k) {
            u0 += A[0*3+k] * V[k*3+i];
            u1 += A[1*3+k] * V[k*3+i];
            u2 += A[2*3+k] * V[k*3+i];
        }
        double nrm = sqrt(u0*u0 + u1*u1 + u2*u2);
        if (nrm > 1e-300) { u0 /= nrm; u1 /= nrm; u2 /= nrm; }
        else {
            double ax = U[0], ay = U[3], az = U[6];
            double bx = U[1], by = U[4], bz = U[7];
            u0 = ay*bz - az*by; u1 = az*bx - ax*bz; u2 = ax*by - ay*bx;
        }
        U[0*3+i] = u0; U[1*3+i] = u1; U[2*3+i] = u2;
    }
}

// R = V @ U^T (reference's R with the V[2][2]*=d quirk). Fast path: when
// det(H) > 0 the quirk is a no-op (d=+1) and R is exactly the transpose of
// the orthogonal polar factor of H -> Newton polar iteration, fixed 10
// iterations (uniform control flow, bit-identical across blocks).
// Fallback (det<=eps): exact Jacobi path.
__device__ void compute_R_f64(const double* H, double* R) {
    double nf = 0.0;
    for (int k = 0; k < 9; ++k) nf += H[k]*H[k];
    if (nf > 0.0) {
        const double sc = 1.0 / sqrt(nf * (1.0/3.0));
        double X[9];
        #pragma unroll
        for (int k = 0; k < 9; ++k) X[k] = H[k] * sc;
        const double d0 = det3(X);
        if (d0 > 1e-12) {
            for (int iter = 0; iter < 10; ++iter) {
                const double dt = det3(X);
                const double g = (iter < 4) ? cbrt(1.0 / dt) : 1.0;
                double Y[9];
                #pragma unroll
                for (int k = 0; k < 9; ++k) Y[k] = g * X[k];
                double C[9];                       // cofactor matrix: Y^{-T} = C/det(Y)
                C[0] = Y[4]*Y[8]-Y[5]*Y[7]; C[1] = Y[5]*Y[6]-Y[3]*Y[8]; C[2] = Y[3]*Y[7]-Y[4]*Y[6];
                C[3] = Y[2]*Y[7]-Y[1]*Y[8]; C[4] = Y[0]*Y[8]-Y[2]*Y[6]; C[5] = Y[1]*Y[6]-Y[0]*Y[7];
                C[6] = Y[1]*Y[5]-Y[2]*Y[4]; C[7] = Y[2]*Y[3]-Y[0]*Y[5]; C[8] = Y[0]*Y[4]-Y[1]*Y[3];
                const double inv = 1.0 / (dt * g * g * g);
                #pragma unroll
                for (int k = 0; k < 9; ++k) X[k] = 0.5 * (Y[k] + C[k] * inv);
            }
            R[0]=X[0]; R[1]=X[3]; R[2]=X[6];
            R[3]=X[1]; R[4]=X[4]; R[5]=X[7];
            R[6]=X[2]; R[7]=X[5]; R[8]=X[8];
            return;
        }
    }
    double U[9], V[9], sig[3];
    svd3x3(H, U, V, sig);
    double d = (det3(U) * det3(V) < 0.0) ? -1.0 : 1.0;
    V[2*3+2] *= d;
    for (int i = 0; i < 3; ++i)
        for (int j = 0; j < 3; ++j) {
            double s = 0.0;
            for (int k = 0; k < 3; ++k) s += V[i*3+k] * U[j*3+k];
            R[i*3+j] = s;
        }
}

__device__ inline float wred(float v) {
    v += __shfl_down(v, 32);
    v += __shfl_down(v, 16);
    v += __shfl_down(v, 8);
    v += __shfl_down(v, 4);
    v += __shfl_down(v, 2);
    v += __shfl_down(v, 1);
    return v;   // valid on lane 0 of each wave
}

__device__ __forceinline__ void tf3(const float* __restrict__ R, const float* __restrict__ T,
                                    float x, float y, float z,
                                    float& ox, float& oy, float& oz) {
    ox = x*R[0] + y*R[3] + z*R[6] + T[0];
    oy = x*R[1] + y*R[4] + z*R[7] + T[1];
    oz = x*R[2] + y*R[5] + z*R[8] + T[2];
}

// One launch per ICP iteration. 256 blocks: b = bid>>6, blk = bid&63.
// Phase 1 (it>0): every block redundantly reduces nnR -> err, H -> polar ->
//   incremental R,t -> composes cumulative rc[b][it] (bit-identical across blocks).
// Phase 2 (it<=10, not done): NN for iteration it. Each block owns QPB=32
//   queries and scans ALL N candidates (staged+transformed in LDS, bank-rotated)
//   -> block-local argmin, plain u64 stores, ZERO atomics.
// Finalize (done or it==11): blk==0 blocks compute _get_transform(p1, rc(p1)).
__global__ void __launch_bounds__(BT) k_iter(const float* __restrict__ p1,
                                             const float* __restrict__ p2,
                                             float* __restrict__ out,
                                             const unsigned long long* __restrict__ nnR,
                                             unsigned long long* __restrict__ nnW,
                                             double* __restrict__ rc,
                                             float* __restrict__ errs,
                                             int* __restrict__ doneflag,
                                             int it) {
    const int bid = blockIdx.x, tid = threadIdx.x;
    const int b = bid >> 6, blk = bid & 63;
    const int lane = tid & 63, wave = tid >> 6;

    __shared__ float4 sc4[N];              // 32 KB: all candidates, bank-rotated
    __shared__ float sScore[NSTR][QPB];    // 4 KB
    __shared__ int   sIdx[NSTR][QPB];      // 4 KB
    __shared__ float sPn[QPB];
    __shared__ float sR[9], sT[3];
    __shared__ float lred[4][16];
    __shared__ int sFin;

    if (it == 0) {
        if (tid == 0) {
            sR[0]=1.f; sR[1]=0.f; sR[2]=0.f;
            sR[3]=0.f; sR[4]=1.f; sR[5]=0.f;
            sR[6]=0.f; sR[7]=0.f; sR[8]=1.f;
            sT[0]=0.f; sT[1]=0.f; sT[2]=0.f;
            sFin = 0;
            if (bid == 0) {
                *doneflag = 0;
                for (int bb = 0; bb < B; ++bb) {   // rc[bb][0] = identity
                    double* r0 = rc + (bb*12 + 0)*12;
                    r0[0]=1; r0[1]=0; r0[2]=0; r0[3]=0; r0[4]=1; r0[5]=0;
                    r0[6]=0; r0[7]=0; r0[8]=1; r0[9]=0; r0[10]=0; r0[11]=0;
                }
            }
        }
        __syncthreads();
    } else {
        // cheap cross-launch early exit
        if (tid == 0) sFin = (*doneflag) ? 2 : 0;
        __syncthreads();
        if (sFin == 2) return;

        // ---------- phase 1: reduce nnR (it-1's matches), polar, compose ----------
        const double* rp = rc + (b*12 + (it-1))*12;
        float cR[9], cT[3];
        #pragma unroll
        for (int k = 0; k < 9; ++k) cR[k] = (float)rp[k];
        #pragma unroll
        for (int k = 0; k < 3; ++k) cT[k] = (float)rp[9+k];

        float pv[16];
        #pragma unroll
        for (int k = 0; k < 16; ++k) pv[k] = 0.f;

        unsigned long long pk3[RPT];
        #pragma unroll
        for (int u = 0; u < RPT; ++u)
            pk3[u] = nnR[3*N + (tid + u*BT)];      // reference quirk: idx[-1]
        int mi[RPT];
        #pragma unroll
        for (int u = 0; u < RPT; ++u)
            mi[u] = (int)(unsigned int)(pk3[u] & 0xffffffffULL);
        float mxa[RPT], mya[RPT], mza[RPT];
        #pragma unroll
        for (int u = 0; u < RPT; ++u) {
            const float* mp = &p2[(b*N + mi[u])*3];
            mxa[u] = mp[0]; mya[u] = mp[1]; mza[u] = mp[2];
        }
        float pxa[RPT], pya[RPT], pza[RPT];
        #pragma unroll
        for (int u = 0; u < RPT; ++u) {
            const float* pp = &p1[(b*N + (tid + u*BT))*3];
            pxa[u] = pp[0]; pya[u] = pp[1]; pza[u] = pp[2];
        }
        #pragma unroll
        for (int u = 0; u < RPT; ++u) {
            float tx, ty, tz;
            tf3(cR, cT, pxa[u], pya[u], pza[u], tx, ty, tz);   // temp_{it-1}
            const float mx = mxa[u], my = mya[u], mz = mza[u];
            pv[0] += mx;  pv[1] += my;  pv[2] += mz;
            pv[3] += tx;  pv[4] += ty;  pv[5] += tz;
            pv[6] += mx*tx;  pv[7]  += mx*ty;  pv[8]  += mx*tz;
            pv[9] += my*tx;  pv[10] += my*ty;  pv[11] += my*tz;
            pv[12]+= mz*tx;  pv[13] += mz*ty;  pv[14] += mz*tz;
        }
        for (int r = tid; r < B*N; r += BT)              // err over ALL batches
            pv[15] += sqrtf(__uint_as_float((unsigned int)(nnR[r] >> 32)));
        #pragma unroll
        for (int k = 0; k < 16; ++k) pv[k] = wred(pv[k]);
        if (lane == 0) {
            #pragma unroll
            for (int k = 0; k < 16; ++k) lred[wave][k] = pv[k];
        }
        __syncthreads();
        if (tid == 0) {
            float a[16];
            #pragma unroll
            for (int k = 0; k < 16; ++k)
                a[k] = lred[0][k] + lred[1][k] + lred[2][k] + lred[3][k];
            const float errcur  = a[15] / (float)(B*N);
            const float errprev = (it >= 2) ? errs[it-2] : 0.0f;
            const int done = (fabsf(errprev - errcur) < TOL) ? 1 : 0;
            errs[it-1] = errcur;          // identical value from every block: benign

            double c2d[3] = { (double)a[0]/N, (double)a[1]/N, (double)a[2]/N };
            double c1d[3] = { (double)a[3]/N, (double)a[4]/N, (double)a[5]/N };
            double H[9];
            for (int j = 0; j < 3; ++j)
                for (int k = 0; k < 3; ++k)
                    H[j*3+k] = (double)a[6 + j*3 + k] - (double)N * c2d[j] * c1d[k];
            double Rinc[9], tinc[3];
            compute_R_f64(H, Rinc);
            for (int j = 0; j < 3; ++j)
                tinc[j] = c2d[j] - (c1d[0]*Rinc[0*3+j] + c1d[1]*Rinc[1*3+j] + c1d[2]*Rinc[2*3+j]);
            // compose: Rc_new = Rc_old @ Rinc ; tc_new = tc_old @ Rinc + tinc
            double Rn[9], tn[3];
            for (int i = 0; i < 3; ++i)
                for (int j = 0; j < 3; ++j)
                    Rn[i*3+j] = rp[i*3+0]*Rinc[0*3+j] + rp[i*3+1]*Rinc[1*3+j] + rp[i*3+2]*Rinc[2*3+j];
            for (int j = 0; j < 3; ++j)
                tn[j] = rp[9+0]*Rinc[0*3+j] + rp[9+1]*Rinc[1*3+j] + rp[9+2]*Rinc[2*3+j] + tinc[j];
            double* rn = rc + (b*12 + it)*12;
            for (int k = 0; k < 9; ++k) { rn[k] = Rn[k]; sR[k] = (float)Rn[k]; }
            for (int k = 0; k < 3; ++k) { rn[9+k] = tn[k]; sT[k] = (float)tn[k]; }
            sFin = (done || it == MAXIT) ? 1 : 0;
        }
        __syncthreads();
    }

    if (sFin == 1) {
        // ---------- finalize: _get_transform(p1, temp_final) ----------
        if (blk != 0) return;
        float pv[16];
        #pragma unroll
        for (int k = 0; k < 16; ++k) pv[k] = 0.f;
        for (int i = tid; i < N; i += BT) {
            const float* pp = &p1[(b*N + i)*3];
            const float px = pp[0], py = pp[1], pz = pp[2];
            float tx, ty, tz;
            tf3(sR, sT, px, py, pz, tx, ty, tz);        // temp_final
            pv[0] += tx; pv[1] += ty; pv[2] += tz;
            pv[3] += px; pv[4] += py; pv[5] += pz;
            pv[6] += tx*px;  pv[7]  += tx*py;  pv[8]  += tx*pz;
            pv[9] += ty*px;  pv[10] += ty*py;  pv[11] += ty*pz;
            pv[12]+= tz*px;  pv[13] += tz*py;  pv[14] += tz*pz;
        }
        #pragma unroll
        for (int k = 0; k < 15; ++k) pv[k] = wred(pv[k]);
        if (lane == 0) {
            #pragma unroll
            for (int k = 0; k < 15; ++k) lred[wave][k] = pv[k];
        }
        __syncthreads();
        if (tid == 0) {
            float a[15];
            #pragma unroll
            for (int k = 0; k < 15; ++k)
                a[k] = lred[0][k] + lred[1][k] + lred[2][k] + lred[3][k];
            double c2d[3] = { (double)a[0]/N, (double)a[1]/N, (double)a[2]/N };
            double c1d[3] = { (double)a[3]/N, (double)a[4]/N, (double)a[5]/N };
            double H[9];
            for (int j = 0; j < 3; ++j)
                for (int k = 0; k < 3; ++k)
                    H[j*3+k] = (double)a[6 + j*3 + k] - (double)N * c2d[j] * c1d[k];
            double Rf[9];
            compute_R_f64(H, Rf);
            for (int i = 0; i < 3; ++i) {
                out[b*12 + i*4 + 0] = (float)Rf[i*3+0];
                out[b*12 + i*4 + 1] = (float)Rf[i*3+1];
                out[b*12 + i*4 + 2] = (float)Rf[i*3+2];
                const double tj = c2d[i] - (c1d[0]*Rf[0*3+i] + c1d[1]*Rf[1*3+i] + c1d[2]*Rf[2*3+i]);
                out[b*12 + i*4 + 3] = (float)tj;
            }
            *doneflag = 1;
        }
        return;
    }

    // ---------- phase 2: NN for iteration it (atomic-free) ----------
    {
        // stage ALL candidates of batch b, transformed, bank-rotated:
        // candidate c -> slot (c>>6)*64 + (((c&63)+(c>>6))&63). Stripe reads then
        // hit banks 4*((j+st)&63)%32: distinct for the 8 stripes in a wave.
        for (int c = tid; c < N; c += BT) {
            const float* cp = &p1[(b*N + c)*3];
            float cx, cy, cz;
            tf3(sR, sT, cp[0], cp[1], cp[2], cx, cy, cz);
            const int s = c >> 6, jj = c & 63;
            sc4[s*64 + ((jj + s) & 63)] =
                make_float4(cx, cy, cz, 0.5f*(cx*cx + cy*cy + cz*cz));
        }
        __syncthreads();

        const int qg = tid & 7, st = tid >> 3;   // 8 query-groups x 32 stripes
        float px[4], py[4], pz[4];
        #pragma unroll
        for (int k = 0; k < 4; ++k) {
            const int q = blk*QPB + qg*4 + k;
            const float* pp = &p2[(b*N + q)*3];
            px[k] = pp[0]; py[k] = pp[1]; pz[k] = pp[2];
        }
        if (st == 0) {
            #pragma unroll
            for (int k = 0; k < 4; ++k)
                sPn[qg*4 + k] = px[k]*px[k] + py[k]*py[k] + pz[k]*pz[k];
        }
        float bs[4]; int bj[4];
        #pragma unroll
        for (int k = 0; k < 4; ++k) { bs[k] = __uint_as_float(0x7f7fffffu); bj[k] = 0; }
        const int base = st * CPS;
        for (int j = 0; j < CPS; ++j) {
            const float4 cd = sc4[base + ((j + st) & (CPS-1))];
            const int cidx = base + j;
            #pragma unroll
            for (int k = 0; k < 4; ++k) {
                float s = __builtin_fmaf(-px[k], cd.x,
                          __builtin_fmaf(-py[k], cd.y,
                          __builtin_fmaf(-pz[k], cd.z, cd.w)));
                if (s < bs[k]) { bs[k] = s; bj[k] = cidx; }
            }
        }
        #pragma unroll
        for (int k = 0; k < 4; ++k) {
            sScore[st][qg*4 + k] = bs[k];
            sIdx[st][qg*4 + k]   = bj[k];
        }
        __syncthreads();
        if (tid < QPB) {
            // first-min across stripes (ascending candidate index = first occurrence)
            float fb = sScore[0][tid]; int fj = sIdx[0][tid];
            #pragma unroll 8
            for (int s = 1; s < NSTR; ++s) {
                const float v = sScore[s][tid]; const int vi = sIdx[s][tid];
                if (v < fb || (v == fb && vi < fj)) { fb = v; fj = vi; }
            }
            const float d2 = fmaxf(__builtin_fmaf(2.0f, fb, sPn[tid]), 0.0f);
            nnW[b*N + blk*QPB + tid] =
                ((unsigned long long)__float_as_uint(d2) << 32) | (unsigned int)fj;
        }
    }
}

extern "C" void kernel_launch(void* const* d_in, const int* in_sizes, int n_in,
                              void* d_out, int out_size, void* d_ws, size_t ws_size,
                              hipStream_t stream) {
    const float* p1 = (const float*)d_in[0];
    const float* p2 = (const float*)d_in[1];
    float* out = (float*)d_out;
    unsigned long long* nnA = (unsigned long long*)d_ws;
    unsigned long long* nnB = (unsigned long long*)((char*)d_ws + 65536);
    double* rc   = (double*)((char*)d_ws + 131072);
    float* errs  = (float*)((char*)d_ws + 135680);
    int* doneflag = (int*)((char*)d_ws + 135728);

    // no memsets needed: nn slots are fully overwritten by plain stores before
    // any read (ping-pong across launches); doneflag/rc initialized at it==0.
    for (int it = 0; it <= MAXIT; ++it) {
        unsigned long long* w = (it & 1) ? nnB : nnA;          // written this it
        unsigned long long* r = (it & 1) ? nnA : nnB;          // written last it
        k_iter<<<NBLK, BT, 0, stream>>>(p1, p2, out, r, w, rc, errs, doneflag, it);
    }
}

// Round 7
// 260.972 us; speedup vs baseline: 2.0854x; 1.3492x over previous
//
#include <hip/hip_runtime.h>

#define B 4
#define N 2048
#define MAXIT 11        // bodies it=0..10; launch it=11 is finalize-only
#define TOL 1e-4f
#define BT 256
#define NBLK 256
#define QPB 32         // queries per block
#define NSTR 32        // candidate stripes per block
#define CPS 64         // candidates per stripe

// ---------------- workspace layout (ping-pong partials: no memsets needed) ----
// [0,     12288) f32 GpA[64][4][12]   (G-partials: {sum m(3), sum m (x) p1(9)})
// [12288, 24576) f32 GpB[64][4][12]
// [24576, 25600) f32 errpA[256]       (per-block sum of sqrt(d2) over 32 queries)
// [25600, 26624) f32 errpB[256]
// [26624, 31232) f64 rc[B][12][12]    (cumulative R(9)+t(3) per batch per launch)
// [31232, 31280) f32 errs[12]
// [31280, 31284) int doneflag         (0 or finalize-launch-index+1)
// [31284, 31332) f32 p1s[B][3]        (sum of p1 per batch, written at it=0)

// ---------------- 3x3 helpers (double, thread-serial) ----------------
__device__ double det3(const double* M) {
    return M[0]*(M[4]*M[8]-M[5]*M[7])
         - M[1]*(M[3]*M[8]-M[5]*M[6])
         + M[2]*(M[3]*M[7]-M[4]*M[6]);
}

__device__ void svd3x3(const double* A, double* U, double* V, double* sig) {
    double S[9];
    for (int i = 0; i < 3; ++i)
        for (int j = 0; j < 3; ++j) {
            double s = 0.0;
            for (int k = 0; k < 3; ++k) s += A[k*3+i] * A[k*3+j];
            S[i*3+j] = s;
        }
    double Vm[9] = {1,0,0, 0,1,0, 0,0,1};
    for (int sweep = 0; sweep < 30; ++sweep) {
        double off = fabs(S[1]) + fabs(S[2]) + fabs(S[5]);
        double base = fabs(S[0]) + fabs(S[4]) + fabs(S[8]);
        if (off <= 1e-15 * base) break;
        for (int pi = 0; pi < 3; ++pi) {
            const int p = (pi == 2) ? 1 : 0;
            const int q = (pi == 0) ? 1 : 2;
            double apq = S[p*3+q];
            if (apq == 0.0) continue;
            double app = S[p*3+p], aqq = S[q*3+q];
            double tau = (aqq - app) / (2.0 * apq);
            double tt  = ((tau >= 0.0) ? 1.0 : -1.0) / (fabs(tau) + sqrt(1.0 + tau*tau));
            double c = 1.0 / sqrt(1.0 + tt*tt);
            double s = tt * c;
            for (int k = 0; k < 3; ++k) {
                double skp = S[k*3+p], skq = S[k*3+q];
                S[k*3+p] = c*skp - s*skq;
                S[k*3+q] = s*skp + c*skq;
            }
            for (int k = 0; k < 3; ++k) {
                double spk = S[p*3+k], sqk = S[q*3+k];
                S[p*3+k] = c*spk - s*sqk;
                S[q*3+k] = s*spk + c*sqk;
            }
            for (int k = 0; k < 3; ++k) {
                double vkp = Vm[k*3+p], vkq = Vm[k*3+q];
                Vm[k*3+p] = c*vkp - s*vkq;
                Vm[k*3+q] = s*vkp + c*vkq;
            }
        }
    }
    double lam[3] = {S[0], S[4], S[8]};
    int ord[3] = {0, 1, 2};
    for (int i = 0; i < 2; ++i)
        for (int j = i+1; j < 3; ++j)
            if (lam[ord[j]] > lam[ord[i]]) { int tmp = ord[i]; ord[i] = ord[j]; ord[j] = tmp; }
    for (int i = 0; i < 3; ++i) {
        int o = ord[i];
        double l = lam[o] > 0.0 ? lam[o] : 0.0;
        sig[i] = sqrt(l);
        for (int k = 0; k < 3; ++k) V[k*3+i] = Vm[k*3+o];
    }
    for (int i = 0; i < 3; ++i) {
        double u0 = 0, u1 = 0, u2 = 0;
        for (int k = 0; k < 3; ++k) {
            u0 += A[0*3+k] * V[k*3+i];
            u1 += A[1*3+k] * V[k*3+i];
            u2 += A[2*3+k] * V[k*3+i];
        }
        double nrm = sqrt(u0*u0 + u1*u1 + u2*u2);
        if (nrm > 1e-300) { u0 /= nrm; u1 /= nrm; u2 /= nrm; }
        else {
            double ax = U[0], ay = U[3], az = U[6];
            double bx = U[1], by = U[4], bz = U[7];
            u0 = ay*bz - az*by; u1 = az*bx - ax*bz; u2 = ax*by - ay*bx;
        }
        U[0*3+i] = u0; U[1*3+i] = u1; U[2*3+i] = u2;
    }
}

// R = V @ U^T (reference's R incl. the V[2][2]*=d quirk). Fast path det(H)>0:
// Newton polar iteration, fixed count (bit-identical across blocks).
__device__ void compute_R_f64(const double* H, double* R) {
    double nf = 0.0;
    for (int k = 0; k < 9; ++k) nf += H[k]*H[k];
    if (nf > 0.0) {
        const double sc = 1.0 / sqrt(nf * (1.0/3.0));
        double X[9];
        #pragma unroll
        for (int k = 0; k < 9; ++k) X[k] = H[k] * sc;
        const double d0 = det3(X);
        if (d0 > 1e-12) {
            for (int iter = 0; iter < 10; ++iter) {
                const double dt = det3(X);
                const double g = (iter < 4) ? cbrt(1.0 / dt) : 1.0;
                double Y[9];
                #pragma unroll
                for (int k = 0; k < 9; ++k) Y[k] = g * X[k];
                double C[9];
                C[0] = Y[4]*Y[8]-Y[5]*Y[7]; C[1] = Y[5]*Y[6]-Y[3]*Y[8]; C[2] = Y[3]*Y[7]-Y[4]*Y[6];
                C[3] = Y[2]*Y[7]-Y[1]*Y[8]; C[4] = Y[0]*Y[8]-Y[2]*Y[6]; C[5] = Y[1]*Y[6]-Y[0]*Y[7];
                C[6] = Y[1]*Y[5]-Y[2]*Y[4]; C[7] = Y[2]*Y[3]-Y[0]*Y[5]; C[8] = Y[0]*Y[4]-Y[1]*Y[3];
                const double inv = 1.0 / (dt * g * g * g);
                #pragma unroll
                for (int k = 0; k < 9; ++k) X[k] = 0.5 * (Y[k] + C[k] * inv);
            }
            R[0]=X[0]; R[1]=X[3]; R[2]=X[6];
            R[3]=X[1]; R[4]=X[4]; R[5]=X[7];
            R[6]=X[2]; R[7]=X[5]; R[8]=X[8];
            return;
        }
    }
    double U[9], V[9], sig[3];
    svd3x3(H, U, V, sig);
    double d = (det3(U) * det3(V) < 0.0) ? -1.0 : 1.0;
    V[2*3+2] *= d;
    for (int i = 0; i < 3; ++i)
        for (int j = 0; j < 3; ++j) {
            double s = 0.0;
            for (int k = 0; k < 3; ++k) s += V[i*3+k] * U[j*3+k];
            R[i*3+j] = s;
        }
}

__device__ inline float wred(float v) {
    v += __shfl_down(v, 32);
    v += __shfl_down(v, 16);
    v += __shfl_down(v, 8);
    v += __shfl_down(v, 4);
    v += __shfl_down(v, 2);
    v += __shfl_down(v, 1);
    return v;   // valid on lane 0 of each wave
}

__device__ __forceinline__ void tf3(const float* __restrict__ R, const float* __restrict__ T,
                                    float x, float y, float z,
                                    float& ox, float& oy, float& oz) {
    ox = x*R[0] + y*R[3] + z*R[6] + T[0];
    oy = x*R[1] + y*R[4] + z*R[7] + T[1];
    oz = x*R[2] + y*R[5] + z*R[8] + T[2];
}

// One launch per ICP iteration. 256 blocks: b = bid>>6, blk = bid&63.
// Phase 1 (it>0): tiny — reduce 64 G-partials + 256 err-partials (written by the
//   PREVIOUS launch's NN phase), rebuild H analytically (H bilinear in R), polar,
//   compose rc[b][it]. Redundant per block, bit-identical.
// Phase 2: NN (block-local argmin over all N candidates staged in LDS); writes
//   err-partial per block; batch-3 blocks also write G-partials for all batches
//   (reference's matched = p2[:, idx[-1]] quirk).
__global__ void __launch_bounds__(BT) k_iter(const float* __restrict__ p1,
                                             const float* __restrict__ p2,
                                             float* __restrict__ out,
                                             const float* __restrict__ rGp,
                                             float* __restrict__ wGp,
                                             const float* __restrict__ rerrp,
                                             float* __restrict__ werrp,
                                             double* __restrict__ rc,
                                             float* __restrict__ errs,
                                             int* __restrict__ doneflag,
                                             float* __restrict__ p1s,
                                             int it) {
    const int bid = blockIdx.x, tid = threadIdx.x;
    const int b = bid >> 6, blk = bid & 63;
    const int lane = tid & 63, wave = tid >> 6;

    __shared__ float4 sc4[N];              // 32 KB candidates, bank-rotated
    __shared__ float sScore[NSTR][QPB];
    __shared__ int   sIdx[NSTR][QPB];
    __shared__ float sPn[QPB], sD2[QPB];
    __shared__ int   sMi[QPB];
    __shared__ float sR[9], sT[3];
    __shared__ float lred[4][16];
    __shared__ int sFin;

    if (it == 0) {
        if (tid == 0) {
            sR[0]=1.f; sR[1]=0.f; sR[2]=0.f;
            sR[3]=0.f; sR[4]=1.f; sR[5]=0.f;
            sR[6]=0.f; sR[7]=0.f; sR[8]=1.f;
            sT[0]=0.f; sT[1]=0.f; sT[2]=0.f;
            sFin = 0;
            if (bid == 0) {
                *doneflag = 0;
                for (int bb = 0; bb < B; ++bb) {
                    double* r0 = rc + (bb*12 + 0)*12;
                    r0[0]=1; r0[1]=0; r0[2]=0; r0[3]=0; r0[4]=1; r0[5]=0;
                    r0[6]=0; r0[7]=0; r0[8]=1; r0[9]=0; r0[10]=0; r0[11]=0;
                }
            }
        }
        __syncthreads();
    } else {
        // early exit only for launches strictly after the finalize launch
        { const int df = *doneflag; if (df != 0 && df <= it) return; }

        // ---------- phase 1: reduce partials, rebuild H, polar, compose ------
        float g12[12];
        if (wave == 0) {
            const float* gp = rGp + (lane*4 + b)*12;    // Gp[blk=lane][b][12]
            const float4 a0 = *(const float4*)(gp);
            const float4 a1 = *(const float4*)(gp + 4);
            const float4 a2 = *(const float4*)(gp + 8);
            g12[0]=a0.x; g12[1]=a0.y; g12[2]=a0.z; g12[3]=a0.w;
            g12[4]=a1.x; g12[5]=a1.y; g12[6]=a1.z; g12[7]=a1.w;
            g12[8]=a2.x; g12[9]=a2.y; g12[10]=a2.z; g12[11]=a2.w;
            #pragma unroll
            for (int k = 0; k < 12; ++k) g12[k] = wred(g12[k]);
        }
        float er = rerrp[tid];
        er = wred(er);
        if (lane == 0) lred[wave][0] = er;
        __syncthreads();
        if (tid == 0) {
            const float ersum = lred[0][0]+lred[1][0]+lred[2][0]+lred[3][0];
            const float errcur = ersum / (float)(B*N);
            const float errprev = (it >= 2) ? errs[it-2] : 0.0f;
            const int done = (fabsf(errprev - errcur) < TOL) ? 1 : 0;
            errs[it-1] = errcur;

            const double* rp = rc + (b*12 + (it-1))*12;
            double RP[12];
            for (int k = 0; k < 12; ++k) RP[k] = rp[k];
            const double sm0 = g12[0], sm1 = g12[1], sm2 = g12[2];
            double G[9];
            for (int k = 0; k < 9; ++k) G[k] = (double)g12[3+k];
            const double p1b0 = (double)p1s[b*3+0]/N;
            const double p1b1 = (double)p1s[b*3+1]/N;
            const double p1b2 = (double)p1s[b*3+2]/N;
            const double c2d[3] = { sm0/N, sm1/N, sm2/N };
            const double smv[3] = { sm0, sm1, sm2 };
            double c1d[3], H[9];
            for (int k = 0; k < 3; ++k)
                c1d[k] = p1b0*RP[0*3+k] + p1b1*RP[1*3+k] + p1b2*RP[2*3+k] + RP[9+k];
            for (int j = 0; j < 3; ++j)
                for (int k = 0; k < 3; ++k) {
                    const double M = G[j*3+0]*RP[0*3+k] + G[j*3+1]*RP[1*3+k]
                                   + G[j*3+2]*RP[2*3+k] + smv[j]*RP[9+k];
                    H[j*3+k] = M - (double)N * c2d[j] * c1d[k];
                }
            double Rinc[9], tinc[3];
            compute_R_f64(H, Rinc);
            for (int j = 0; j < 3; ++j)
                tinc[j] = c2d[j] - (c1d[0]*Rinc[0*3+j] + c1d[1]*Rinc[1*3+j] + c1d[2]*Rinc[2*3+j]);
            double Rn[9], tn[3];
            for (int i = 0; i < 3; ++i)
                for (int j = 0; j < 3; ++j)
                    Rn[i*3+j] = RP[i*3+0]*Rinc[0*3+j] + RP[i*3+1]*Rinc[1*3+j] + RP[i*3+2]*Rinc[2*3+j];
            for (int j = 0; j < 3; ++j)
                tn[j] = RP[9+0]*Rinc[0*3+j] + RP[9+1]*Rinc[1*3+j] + RP[9+2]*Rinc[2*3+j] + tinc[j];
            double* rn = rc + (b*12 + it)*12;
            for (int k = 0; k < 9; ++k) { rn[k] = Rn[k]; sR[k] = (float)Rn[k]; }
            for (int k = 0; k < 3; ++k) { rn[9+k] = tn[k]; sT[k] = (float)tn[k]; }
            sFin = (done || it == MAXIT) ? 1 : 0;
        }
        __syncthreads();
    }

    if (sFin == 1) {
        // ---------- finalize: _get_transform(p1, temp_final) ----------
        if (blk != 0) return;
        float pv[16];
        #pragma unroll
        for (int k = 0; k < 16; ++k) pv[k] = 0.f;
        for (int i = tid; i < N; i += BT) {
            const float* pp = &p1[(b*N + i)*3];
            const float px = pp[0], py = pp[1], pz = pp[2];
            float tx, ty, tz;
            tf3(sR, sT, px, py, pz, tx, ty, tz);        // temp_final
            pv[0] += tx; pv[1] += ty; pv[2] += tz;
            pv[3] += px; pv[4] += py; pv[5] += pz;
            pv[6] += tx*px;  pv[7]  += tx*py;  pv[8]  += tx*pz;
            pv[9] += ty*px;  pv[10] += ty*py;  pv[11] += ty*pz;
            pv[12]+= tz*px;  pv[13] += tz*py;  pv[14] += tz*pz;
        }
        #pragma unroll
        for (int k = 0; k < 15; ++k) pv[k] = wred(pv[k]);
        if (lane == 0) {
            #pragma unroll
            for (int k = 0; k < 15; ++k) lred[wave][k] = pv[k];
        }
        __syncthreads();
        if (tid == 0) {
            float a[15];
            #pragma unroll
            for (int k = 0; k < 15; ++k)
                a[k] = lred[0][k] + lred[1][k] + lred[2][k] + lred[3][k];
            double c2d[3] = { (double)a[0]/N, (double)a[1]/N, (double)a[2]/N };
            double c1d[3] = { (double)a[3]/N, (double)a[4]/N, (double)a[5]/N };
            double H[9];
            for (int j = 0; j < 3; ++j)
                for (int k = 0; k < 3; ++k)
                    H[j*3+k] = (double)a[6 + j*3 + k] - (double)N * c2d[j] * c1d[k];
            double Rf[9];
            compute_R_f64(H, Rf);
            for (int i = 0; i < 3; ++i) {
                out[b*12 + i*4 + 0] = (float)Rf[i*3+0];
                out[b*12 + i*4 + 1] = (float)Rf[i*3+1];
                out[b*12 + i*4 + 2] = (float)Rf[i*3+2];
                const double tj = c2d[i] - (c1d[0]*Rf[0*3+i] + c1d[1]*Rf[1*3+i] + c1d[2]*Rf[2*3+i]);
                out[b*12 + i*4 + 3] = (float)tj;
            }
            *doneflag = it + 1;
        }
        return;
    }

    // ---------- phase 2: NN + fused partial reductions ----------
    // stage all candidates of batch b, transformed, bank-rotated
    for (int c = tid; c < N; c += BT) {
        const float* cp = &p1[(b*N + c)*3];
        float cx, cy, cz;
        tf3(sR, sT, cp[0], cp[1], cp[2], cx, cy, cz);
        const int s = c >> 6, jj = c & 63;
        sc4[s*64 + ((jj + s) & 63)] =
            make_float4(cx, cy, cz, 0.5f*(cx*cx + cy*cy + cz*cz));
    }
    __syncthreads();

    if (it == 0 && blk == 0) {
        // p1 sums (identity transform at it=0 -> sc4 holds p1)
        float sx = 0.f, sy = 0.f, sz = 0.f;
        for (int i = tid; i < N; i += BT) {
            const float4 v = sc4[i];
            sx += v.x; sy += v.y; sz += v.z;
        }
        sx = wred(sx); sy = wred(sy); sz = wred(sz);
        if (lane == 0) { lred[wave][0]=sx; lred[wave][1]=sy; lred[wave][2]=sz; }
    }

    const int qg = tid & 7, st = tid >> 3;   // 8 query-groups x 32 stripes
    float px[4], py[4], pz[4];
    #pragma unroll
    for (int k = 0; k < 4; ++k) {
        const int q = blk*QPB + qg*4 + k;
        const float* pp = &p2[(b*N + q)*3];
        px[k] = pp[0]; py[k] = pp[1]; pz[k] = pp[2];
    }
    if (st == 0) {
        #pragma unroll
        for (int k = 0; k < 4; ++k)
            sPn[qg*4 + k] = px[k]*px[k] + py[k]*py[k] + pz[k]*pz[k];
    }
    float bs[4]; int bj[4];
    #pragma unroll
    for (int k = 0; k < 4; ++k) { bs[k] = __uint_as_float(0x7f7fffffu); bj[k] = 0; }
    const int base = st * CPS;
    for (int j = 0; j < CPS; ++j) {
        const float4 cd = sc4[base + ((j + st) & (CPS-1))];
        const int cidx = base + j;
        #pragma unroll
        for (int k = 0; k < 4; ++k) {
            float s = __builtin_fmaf(-px[k], cd.x,
                      __builtin_fmaf(-py[k], cd.y,
                      __builtin_fmaf(-pz[k], cd.z, cd.w)));
            if (s < bs[k]) { bs[k] = s; bj[k] = cidx; }
        }
    }
    #pragma unroll
    for (int k = 0; k < 4; ++k) {
        sScore[st][qg*4 + k] = bs[k];
        sIdx[st][qg*4 + k]   = bj[k];
    }
    __syncthreads();

    if (it == 0 && blk == 0 && tid == 0) {
        p1s[b*3+0] = lred[0][0]+lred[1][0]+lred[2][0]+lred[3][0];
        p1s[b*3+1] = lred[0][1]+lred[1][1]+lred[2][1]+lred[3][1];
        p1s[b*3+2] = lred[0][2]+lred[1][2]+lred[2][2]+lred[3][2];
    }

    if (tid < QPB) {
        // first-min across stripes (ascending idx = first occurrence, jnp.argmin)
        float fb = sScore[0][tid]; int fj = sIdx[0][tid];
        #pragma unroll 8
        for (int s = 1; s < NSTR; ++s) {
            const float v = sScore[s][tid]; const int vi = sIdx[s][tid];
            if (v < fb || (v == fb && vi < fj)) { fb = v; fj = vi; }
        }
        const float d2 = fmaxf(__builtin_fmaf(2.0f, fb, sPn[tid]), 0.0f);
        sMi[tid] = fj;
        sD2[tid] = d2;
    }
    __syncthreads();

    // err partial: sum sqrt(d2) over this block's 32 queries
    if (tid < 64) {
        float e = (tid < QPB) ? sqrtf(sD2[tid]) : 0.f;
        e = wred(e);
        if (tid == 0) werrp[bid] = e;
    }

    // G partials: only batch-3 blocks (reference quirk: matched = p2[:, idx[-1]])
    if (b == 3 && tid < 128) {
        const int bb = tid >> 5, nl = tid & 31;
        const int mi = sMi[nl];
        const float* mp = &p2[(bb*N + mi)*3];
        const float mx = mp[0], my = mp[1], mz = mp[2];
        const float* pp = &p1[(bb*N + blk*QPB + nl)*3];
        const float qx = pp[0], qy = pp[1], qz = pp[2];
        float g[12] = { mx, my, mz,
                        mx*qx, mx*qy, mx*qz,
                        my*qx, my*qy, my*qz,
                        mz*qx, mz*qy, mz*qz };
        #pragma unroll
        for (int k = 0; k < 12; ++k) {
            #pragma unroll
            for (int o = 16; o; o >>= 1)
                g[k] += __shfl_xor(g[k], o, 32);
        }
        if (nl == 0) {
            float* gp = wGp + (blk*4 + bb)*12;
            #pragma unroll
            for (int k = 0; k < 12; ++k) gp[k] = g[k];
        }
    }
}

extern "C" void kernel_launch(void* const* d_in, const int* in_sizes, int n_in,
                              void* d_out, int out_size, void* d_ws, size_t ws_size,
                              hipStream_t stream) {
    const float* p1 = (const float*)d_in[0];
    const float* p2 = (const float*)d_in[1];
    float* out = (float*)d_out;
    float* GpA   = (float*)d_ws;
    float* GpB   = (float*)((char*)d_ws + 12288);
    float* errpA = (float*)((char*)d_ws + 24576);
    float* errpB = (float*)((char*)d_ws + 25600);
    double* rc   = (double*)((char*)d_ws + 26624);
    float* errs  = (float*)((char*)d_ws + 31232);
    int* doneflag = (int*)((char*)d_ws + 31280);
    float* p1s   = (float*)((char*)d_ws + 31284);

    // no memsets: partials ping-pong (written before read each parity),
    // doneflag/rc/p1s initialized inside the it=0 launch.
    for (int it = 0; it <= MAXIT; ++it) {
        float* wG = (it & 1) ? GpB : GpA;
        float* rG = (it & 1) ? GpA : GpB;
        float* wE = (it & 1) ? errpB : errpA;
        float* rE = (it & 1) ? errpA : errpB;
        k_iter<<<NBLK, BT, 0, stream>>>(p1, p2, out, rG, wG, rE, wE,
                                        rc, errs, doneflag, p1s, it);
    }
}

// Round 9
// 250.793 us; speedup vs baseline: 2.1700x; 1.0406x over previous
//
#include <hip/hip_runtime.h>

#define B 4
#define N 2048
#define MAXIT 11        // bodies it=0..10; launch it=11 is finalize-only
#define TOL 1e-4f
#define BT 256
#define NBLK 256
#define QPB 32         // queries per block
#define NSTR 32        // candidate stripes per block
#define CPS 64         // candidates per stripe
#define CPT 8          // candidates per thread (N/BT)

// ---------------- workspace layout (ping-pong partials: no memsets needed) ----
// [0,     12288) f32 GpA[64][4][12]   (G-partials: {sum m(3), sum m (x) p1(9)})
// [12288, 24576) f32 GpB[64][4][12]
// [24576, 25600) f32 errpA[256]       (per-block sum of sqrt(d2) over 32 queries)
// [25600, 26624) f32 errpB[256]
// [26624, 31232) f64 rc[B][12][12]    (cumulative R(9)+t(3) per batch per launch)
// [31232, 31280) f32 errs[12]
// [31280, 31284) int doneflag         (0 or finalize-launch-index+1)
// [31284, 31332) f32 p1s[B][3]        (sum of p1 per batch, written at it=0)

// ---------------- 3x3 helpers (double, thread-serial) ----------------
__device__ double det3(const double* M) {
    return M[0]*(M[4]*M[8]-M[5]*M[7])
         - M[1]*(M[3]*M[8]-M[5]*M[6])
         + M[2]*(M[3]*M[7]-M[4]*M[6]);
}

__device__ void svd3x3(const double* A, double* U, double* V, double* sig) {
    double S[9];
    for (int i = 0; i < 3; ++i)
        for (int j = 0; j < 3; ++j) {
            double s = 0.0;
            for (int k = 0; k < 3; ++k) s += A[k*3+i] * A[k*3+j];
            S[i*3+j] = s;
        }
    double Vm[9] = {1,0,0, 0,1,0, 0,0,1};
    for (int sweep = 0; sweep < 30; ++sweep) {
        double off = fabs(S[1]) + fabs(S[2]) + fabs(S[5]);
        double base = fabs(S[0]) + fabs(S[4]) + fabs(S[8]);
        if (off <= 1e-15 * base) break;
        for (int pi = 0; pi < 3; ++pi) {
            const int p = (pi == 2) ? 1 : 0;
            const int q = (pi == 0) ? 1 : 2;
            double apq = S[p*3+q];
            if (apq == 0.0) continue;
            double app = S[p*3+p], aqq = S[q*3+q];
            double tau = (aqq - app) / (2.0 * apq);
            double tt  = ((tau >= 0.0) ? 1.0 : -1.0) / (fabs(tau) + sqrt(1.0 + tau*tau));
            double c = 1.0 / sqrt(1.0 + tt*tt);
            double s = tt * c;
            for (int k = 0; k < 3; ++k) {
                double skp = S[k*3+p], skq = S[k*3+q];
                S[k*3+p] = c*skp - s*skq;
                S[k*3+q] = s*skp + c*skq;
            }
            for (int k = 0; k < 3; ++k) {
                double spk = S[p*3+k], sqk = S[q*3+k];
                S[p*3+k] = c*spk - s*sqk;
                S[q*3+k] = s*spk + c*sqk;
            }
            for (int k = 0; k < 3; ++k) {
                double vkp = Vm[k*3+p], vkq = Vm[k*3+q];
                Vm[k*3+p] = c*vkp - s*vkq;
                Vm[k*3+q] = s*vkp + c*vkq;
            }
        }
    }
    double lam[3] = {S[0], S[4], S[8]};
    int ord[3] = {0, 1, 2};
    for (int i = 0; i < 2; ++i)
        for (int j = i+1; j < 3; ++j)
            if (lam[ord[j]] > lam[ord[i]]) { int tmp = ord[i]; ord[i] = ord[j]; ord[j] = tmp; }
    for (int i = 0; i < 3; ++i) {
        int o = ord[i];
        double l = lam[o] > 0.0 ? lam[o] : 0.0;
        sig[i] = sqrt(l);
        for (int k = 0; k < 3; ++k) V[k*3+i] = Vm[k*3+o];
    }
    for (int i = 0; i < 3; ++i) {
        double u0 = 0, u1 = 0, u2 = 0;
        for (int k = 0; k < 3; ++k) {
            u0 += A[0*3+k] * V[k*3+i];
            u1 += A[1*3+k] * V[k*3+i];
            u2 += A[2*3+k] * V[k*3+i];
        }
        double nrm = sqrt(u0*u0 + u1*u1 + u2*u2);
        if (nrm > 1e-300) { u0 /= nrm; u1 /= nrm; u2 /= nrm; }
        else {
            double ax = U[0], ay = U[3], az = U[6];
            double bx = U[1], by = U[4], bz = U[7];
            u0 = ay*bz - az*by; u1 = az*bx - ax*bz; u2 = ax*by - ay*bx;
        }
        U[0*3+i] = u0; U[1*3+i] = u1; U[2*3+i] = u2;
    }
}

// R = V @ U^T (reference's R incl. the V[2][2]*=d quirk). Fast path det(H)>0:
// Newton polar iteration, fixed count (bit-identical across blocks).
__device__ void compute_R_f64(const double* H, double* R) {
    double nf = 0.0;
    for (int k = 0; k < 9; ++k) nf += H[k]*H[k];
    if (nf > 0.0) {
        const double sc = 1.0 / sqrt(nf * (1.0/3.0));
        double X[9];
        #pragma unroll
        for (int k = 0; k < 9; ++k) X[k] = H[k] * sc;
        const double d0 = det3(X);
        if (d0 > 1e-12) {
            for (int iter = 0; iter < 10; ++iter) {
                const double dt = det3(X);
                const double g = (iter < 4) ? cbrt(1.0 / dt) : 1.0;
                double Y[9];
                #pragma unroll
                for (int k = 0; k < 9; ++k) Y[k] = g * X[k];
                double C[9];
                C[0] = Y[4]*Y[8]-Y[5]*Y[7]; C[1] = Y[5]*Y[6]-Y[3]*Y[8]; C[2] = Y[3]*Y[7]-Y[4]*Y[6];
                C[3] = Y[2]*Y[7]-Y[1]*Y[8]; C[4] = Y[0]*Y[8]-Y[2]*Y[6]; C[5] = Y[1]*Y[6]-Y[0]*Y[7];
                C[6] = Y[1]*Y[5]-Y[2]*Y[4]; C[7] = Y[2]*Y[3]-Y[0]*Y[5]; C[8] = Y[0]*Y[4]-Y[1]*Y[3];
                const double inv = 1.0 / (dt * g * g * g);
                #pragma unroll
                for (int k = 0; k < 9; ++k) X[k] = 0.5 * (Y[k] + C[k] * inv);
            }
            R[0]=X[0]; R[1]=X[3]; R[2]=X[6];
            R[3]=X[1]; R[4]=X[4]; R[5]=X[7];
            R[6]=X[2]; R[7]=X[5]; R[8]=X[8];
            return;
        }
    }
    double U[9], V[9], sig[3];
    svd3x3(H, U, V, sig);
    double d = (det3(U) * det3(V) < 0.0) ? -1.0 : 1.0;
    V[2*3+2] *= d;
    for (int i = 0; i < 3; ++i)
        for (int j = 0; j < 3; ++j) {
            double s = 0.0;
            for (int k = 0; k < 3; ++k) s += V[i*3+k] * U[j*3+k];
            R[i*3+j] = s;
        }
}

__device__ inline float wred(float v) {
    v += __shfl_down(v, 32);
    v += __shfl_down(v, 16);
    v += __shfl_down(v, 8);
    v += __shfl_down(v, 4);
    v += __shfl_down(v, 2);
    v += __shfl_down(v, 1);
    return v;   // valid on lane 0 of each wave
}

__device__ __forceinline__ void tf3(const float* __restrict__ R, const float* __restrict__ T,
                                    float x, float y, float z,
                                    float& ox, float& oy, float& oz) {
    ox = x*R[0] + y*R[3] + z*R[6] + T[0];
    oy = x*R[1] + y*R[4] + z*R[7] + T[1];
    oz = x*R[2] + y*R[5] + z*R[8] + T[2];
}

// One launch per ICP iteration. 256 blocks: b = bid>>6, blk = bid&63.
// T14 issue-early: the R-independent global loads (p1 candidates, p2 queries)
// are issued into registers at kernel top so their latency hides under phase 1's
// partial-reduction + serial polar. The transform + LDS write happen after
// phase 1 — NN values bit-identical to the round-7 passing kernel (trajectory-
// safe; round-8's query-transform variant changed f32 rounding of err and
// diverged the done-threshold trajectory).
__global__ void __launch_bounds__(BT) k_iter(const float* __restrict__ p1,
                                             const float* __restrict__ p2,
                                             float* __restrict__ out,
                                             const float* __restrict__ rGp,
                                             float* __restrict__ wGp,
                                             const float* __restrict__ rerrp,
                                             float* __restrict__ werrp,
                                             double* __restrict__ rc,
                                             float* __restrict__ errs,
                                             int* __restrict__ doneflag,
                                             float* __restrict__ p1s,
                                             int it) {
    const int bid = blockIdx.x, tid = threadIdx.x;
    const int b = bid >> 6, blk = bid & 63;
    const int lane = tid & 63, wave = tid >> 6;

    __shared__ float4 sc4[N];              // 32 KB candidates, bank-rotated
    __shared__ float sScore[NSTR][QPB];
    __shared__ int   sIdx[NSTR][QPB];
    __shared__ float sPn[QPB], sD2[QPB];
    __shared__ int   sMi[QPB];
    __shared__ float sR[9], sT[3];
    __shared__ float lred[4][16];
    __shared__ int sFin;

    // ---------- T14 issue-early: R-independent register prefetch ----------
    float cvx[CPT], cvy[CPT], cvz[CPT];
    #pragma unroll
    for (int u = 0; u < CPT; ++u) {
        const float* cp = &p1[(b*N + tid + u*BT)*3];
        cvx[u] = cp[0]; cvy[u] = cp[1]; cvz[u] = cp[2];
    }
    const int qg = tid & 7, st = tid >> 3;   // 8 query-groups x 32 stripes
    float qx[4], qy[4], qz[4];
    #pragma unroll
    for (int k = 0; k < 4; ++k) {
        const float* pp = &p2[(b*N + blk*QPB + qg*4 + k)*3];
        qx[k] = pp[0]; qy[k] = pp[1]; qz[k] = pp[2];
    }

    if (it == 0) {
        if (tid == 0) {
            sR[0]=1.f; sR[1]=0.f; sR[2]=0.f;
            sR[3]=0.f; sR[4]=1.f; sR[5]=0.f;
            sR[6]=0.f; sR[7]=0.f; sR[8]=1.f;
            sT[0]=0.f; sT[1]=0.f; sT[2]=0.f;
            sFin = 0;
            if (bid == 0) {
                *doneflag = 0;
                for (int bb = 0; bb < B; ++bb) {
                    double* r0 = rc + (bb*12 + 0)*12;
                    r0[0]=1; r0[1]=0; r0[2]=0; r0[3]=0; r0[4]=1; r0[5]=0;
                    r0[6]=0; r0[7]=0; r0[8]=1; r0[9]=0; r0[10]=0; r0[11]=0;
                }
            }
        }
        __syncthreads();
    } else {
        // early exit only for launches strictly after the finalize launch
        { const int df = *doneflag; if (df != 0 && df <= it) return; }

        // ---------- phase 1: reduce partials, rebuild H, polar, compose ------
        float g12[12];
        if (wave == 0) {
            const float* gp = rGp + (lane*4 + b)*12;    // Gp[blk=lane][b][12]
            const float4 a0 = *(const float4*)(gp);
            const float4 a1 = *(const float4*)(gp + 4);
            const float4 a2 = *(const float4*)(gp + 8);
            g12[0]=a0.x; g12[1]=a0.y; g12[2]=a0.z; g12[3]=a0.w;
            g12[4]=a1.x; g12[5]=a1.y; g12[6]=a1.z; g12[7]=a1.w;
            g12[8]=a2.x; g12[9]=a2.y; g12[10]=a2.z; g12[11]=a2.w;
            #pragma unroll
            for (int k = 0; k < 12; ++k) g12[k] = wred(g12[k]);
        }
        float er = rerrp[tid];
        er = wred(er);
        if (lane == 0) lred[wave][0] = er;
        __syncthreads();
        if (tid == 0) {
            const float ersum = lred[0][0]+lred[1][0]+lred[2][0]+lred[3][0];
            const float errcur = ersum / (float)(B*N);
            const float errprev = (it >= 2) ? errs[it-2] : 0.0f;
            const int done = (fabsf(errprev - errcur) < TOL) ? 1 : 0;
            errs[it-1] = errcur;

            const double* rp = rc + (b*12 + (it-1))*12;
            double RP[12];
            for (int k = 0; k < 12; ++k) RP[k] = rp[k];
            const double sm0 = g12[0], sm1 = g12[1], sm2 = g12[2];
            double G[9];
            for (int k = 0; k < 9; ++k) G[k] = (double)g12[3+k];
            const double p1b0 = (double)p1s[b*3+0]/N;
            const double p1b1 = (double)p1s[b*3+1]/N;
            const double p1b2 = (double)p1s[b*3+2]/N;
            const double c2d[3] = { sm0/N, sm1/N, sm2/N };
            const double smv[3] = { sm0, sm1, sm2 };
            double c1d[3], H[9];
            for (int k = 0; k < 3; ++k)
                c1d[k] = p1b0*RP[0*3+k] + p1b1*RP[1*3+k] + p1b2*RP[2*3+k] + RP[9+k];
            for (int j = 0; j < 3; ++j)
                for (int k = 0; k < 3; ++k) {
                    const double M = G[j*3+0]*RP[0*3+k] + G[j*3+1]*RP[1*3+k]
                                   + G[j*3+2]*RP[2*3+k] + smv[j]*RP[9+k];
                    H[j*3+k] = M - (double)N * c2d[j] * c1d[k];
                }
            double Rinc[9], tinc[3];
            compute_R_f64(H, Rinc);
            for (int j = 0; j < 3; ++j)
                tinc[j] = c2d[j] - (c1d[0]*Rinc[0*3+j] + c1d[1]*Rinc[1*3+j] + c1d[2]*Rinc[2*3+j]);
            double Rn[9], tn[3];
            for (int i = 0; i < 3; ++i)
                for (int j = 0; j < 3; ++j)
                    Rn[i*3+j] = RP[i*3+0]*Rinc[0*3+j] + RP[i*3+1]*Rinc[1*3+j] + RP[i*3+2]*Rinc[2*3+j];
            for (int j = 0; j < 3; ++j)
                tn[j] = RP[9+0]*Rinc[0*3+j] + RP[9+1]*Rinc[1*3+j] + RP[9+2]*Rinc[2*3+j] + tinc[j];
            double* rn = rc + (b*12 + it)*12;
            for (int k = 0; k < 9; ++k) { rn[k] = Rn[k]; sR[k] = (float)Rn[k]; }
            for (int k = 0; k < 3; ++k) { rn[9+k] = tn[k]; sT[k] = (float)tn[k]; }
            sFin = (done || it == MAXIT) ? 1 : 0;
        }
        __syncthreads();
    }

    if (sFin == 1) {
        // ---------- finalize: _get_transform(p1, temp_final) ----------
        if (blk != 0) return;
        float pv[16];
        #pragma unroll
        for (int k = 0; k < 16; ++k) pv[k] = 0.f;
        for (int i = tid; i < N; i += BT) {
            const float* pp = &p1[(b*N + i)*3];
            const float px = pp[0], py = pp[1], pz = pp[2];
            float tx, ty, tz;
            tf3(sR, sT, px, py, pz, tx, ty, tz);        // temp_final
            pv[0] += tx; pv[1] += ty; pv[2] += tz;
            pv[3] += px; pv[4] += py; pv[5] += pz;
            pv[6] += tx*px;  pv[7]  += tx*py;  pv[8]  += tx*pz;
            pv[9] += ty*px;  pv[10] += ty*py;  pv[11] += ty*pz;
            pv[12]+= tz*px;  pv[13] += tz*py;  pv[14] += tz*pz;
        }
        #pragma unroll
        for (int k = 0; k < 15; ++k) pv[k] = wred(pv[k]);
        if (lane == 0) {
            #pragma unroll
            for (int k = 0; k < 15; ++k) lred[wave][k] = pv[k];
        }
        __syncthreads();
        if (tid == 0) {
            float a[15];
            #pragma unroll
            for (int k = 0; k < 15; ++k)
                a[k] = lred[0][k] + lred[1][k] + lred[2][k] + lred[3][k];
            double c2d[3] = { (double)a[0]/N, (double)a[1]/N, (double)a[2]/N };
            double c1d[3] = { (double)a[3]/N, (double)a[4]/N, (double)a[5]/N };
            double H[9];
            for (int j = 0; j < 3; ++j)
                for (int k = 0; k < 3; ++k)
                    H[j*3+k] = (double)a[6 + j*3 + k] - (double)N * c2d[j] * c1d[k];
            double Rf[9];
            compute_R_f64(H, Rf);
            for (int i = 0; i < 3; ++i) {
                out[b*12 + i*4 + 0] = (float)Rf[i*3+0];
                out[b*12 + i*4 + 1] = (float)Rf[i*3+1];
                out[b*12 + i*4 + 2] = (float)Rf[i*3+2];
                const double tj = c2d[i] - (c1d[0]*Rf[0*3+i] + c1d[1]*Rf[1*3+i] + c1d[2]*Rf[2*3+i]);
                out[b*12 + i*4 + 3] = (float)tj;
            }
            *doneflag = it + 1;
        }
        return;
    }

    // ---------- phase 2: NN + fused partial reductions ----------
    // write-late: transform prefetched candidates with the just-computed R,t
    #pragma unroll
    for (int u = 0; u < CPT; ++u) {
        const int c = tid + u*BT;
        float cx, cy, cz;
        tf3(sR, sT, cvx[u], cvy[u], cvz[u], cx, cy, cz);
        const int s = c >> 6, jj = c & 63;
        sc4[s*64 + ((jj + s) & 63)] =
            make_float4(cx, cy, cz, 0.5f*(cx*cx + cy*cy + cz*cz));
    }
    __syncthreads();

    if (it == 0 && blk == 0) {
        // p1 sums (identity transform at it=0 -> sc4 holds p1)
        float sx = 0.f, sy = 0.f, sz = 0.f;
        for (int i = tid; i < N; i += BT) {
            const float4 v = sc4[i];
            sx += v.x; sy += v.y; sz += v.z;
        }
        sx = wred(sx); sy = wred(sy); sz = wred(sz);
        if (lane == 0) { lred[wave][0]=sx; lred[wave][1]=sy; lred[wave][2]=sz; }
    }

    if (st == 0) {
        #pragma unroll
        for (int k = 0; k < 4; ++k)
            sPn[qg*4 + k] = qx[k]*qx[k] + qy[k]*qy[k] + qz[k]*qz[k];
    }
    float bs[4]; int bj[4];
    #pragma unroll
    for (int k = 0; k < 4; ++k) { bs[k] = __uint_as_float(0x7f7fffffu); bj[k] = 0; }
    const int base = st * CPS;
    for (int j = 0; j < CPS; ++j) {
        const float4 cd = sc4[base + ((j + st) & (CPS-1))];
        const int cidx = base + j;
        #pragma unroll
        for (int k = 0; k < 4; ++k) {
            float s = __builtin_fmaf(-qx[k], cd.x,
                      __builtin_fmaf(-qy[k], cd.y,
                      __builtin_fmaf(-qz[k], cd.z, cd.w)));
            if (s < bs[k]) { bs[k] = s; bj[k] = cidx; }
        }
    }
    #pragma unroll
    for (int k = 0; k < 4; ++k) {
        sScore[st][qg*4 + k] = bs[k];
        sIdx[st][qg*4 + k]   = bj[k];
    }
    __syncthreads();

    if (it == 0 && blk == 0 && tid == 0) {
        p1s[b*3+0] = lred[0][0]+lred[1][0]+lred[2][0]+lred[3][0];
        p1s[b*3+1] = lred[0][1]+lred[1][1]+lred[2][1]+lred[3][1];
        p1s[b*3+2] = lred[0][2]+lred[1][2]+lred[2][2]+lred[3][2];
    }

    if (tid < QPB) {
        // first-min across stripes (ascending idx = first occurrence, jnp.argmin)
        float fb = sScore[0][tid]; int fj = sIdx[0][tid];
        #pragma unroll 8
        for (int s = 1; s < NSTR; ++s) {
            const float v = sScore[s][tid]; const int vi = sIdx[s][tid];
            if (v < fb || (v == fb && vi < fj)) { fb = v; fj = vi; }
        }
        const float d2 = fmaxf(__builtin_fmaf(2.0f, fb, sPn[tid]), 0.0f);
        sMi[tid] = fj;
        sD2[tid] = d2;
    }
    __syncthreads();

    // err partial: sum sqrt(d2) over this block's 32 queries
    if (tid < 64) {
        float e = (tid < QPB) ? sqrtf(sD2[tid]) : 0.f;
        e = wred(e);
        if (tid == 0) werrp[bid] = e;
    }

    // G partials: only batch-3 blocks (reference quirk: matched = p2[:, idx[-1]])
    if (b == 3 && tid < 128) {
        const int bb = tid >> 5, nl = tid & 31;
        const int mi = sMi[nl];
        const float* mp = &p2[(bb*N + mi)*3];
        const float mx = mp[0], my = mp[1], mz = mp[2];
        const float* pp = &p1[(bb*N + blk*QPB + nl)*3];
        const float qqx = pp[0], qqy = pp[1], qqz = pp[2];
        float g[12] = { mx, my, mz,
                        mx*qqx, mx*qqy, mx*qqz,
                        my*qqx, my*qqy, my*qqz,
                        mz*qqx, mz*qqy, mz*qqz };
        #pragma unroll
        for (int k = 0; k < 12; ++k) {
            #pragma unroll
            for (int o = 16; o; o >>= 1)
                g[k] += __shfl_xor(g[k], o, 32);
        }
        if (nl == 0) {
            float* gp = wGp + (blk*4 + bb)*12;
            #pragma unroll
            for (int k = 0; k < 12; ++k) gp[k] = g[k];
        }
    }
}

extern "C" void kernel_launch(void* const* d_in, const int* in_sizes, int n_in,
                              void* d_out, int out_size, void* d_ws, size_t ws_size,
                              hipStream_t stream) {
    const float* p1 = (const float*)d_in[0];
    const float* p2 = (const float*)d_in[1];
    float* out = (float*)d_out;
    float* GpA   = (float*)d_ws;
    float* GpB   = (float*)((char*)d_ws + 12288);
    float* errpA = (float*)((char*)d_ws + 24576);
    float* errpB = (float*)((char*)d_ws + 25600);
    double* rc   = (double*)((char*)d_ws + 26624);
    float* errs  = (float*)((char*)d_ws + 31232);
    int* doneflag = (int*)((char*)d_ws + 31280);
    float* p1s   = (float*)((char*)d_ws + 31284);

    for (int it = 0; it <= MAXIT; ++it) {
        float* wG = (it & 1) ? GpB : GpA;
        float* rG = (it & 1) ? GpA : GpB;
        float* wE = (it & 1) ? errpB : errpA;
        float* rE = (it & 1) ? errpA : errpB;
        k_iter<<<NBLK, BT, 0, stream>>>(p1, p2, out, rG, wG, rE, wE,
                                        rc, errs, doneflag, p1s, it);
    }
}